// Round 3
// baseline (4795.564 us; speedup 1.0000x reference)
//
#include <hip/hip_runtime.h>

// ---------------- problem constants ----------------
#define Hd   256
#define Bd   16
#define Td   128
#define Ld   50
#define Vd   32000
#define G5H  1280     // 5*H

typedef __attribute__((ext_vector_type(8))) short short8v;  // 8 bf16 (4 VGPRs)
typedef __attribute__((ext_vector_type(4))) float f32x4;

__device__ __forceinline__ unsigned short f2bu(float f) {   // f32 -> bf16 bits (RNE)
  unsigned u = __float_as_uint(f);
  unsigned r = (u + 0x7fffu + ((u >> 16) & 1u)) >> 16;
  return (unsigned short)r;
}
__device__ __forceinline__ float bu2f(unsigned short b) {
  return __uint_as_float(((unsigned)b) << 16);
}
__device__ __forceinline__ float sigm(float x) { return 1.f / (1.f + __expf(-x)); }

// ---------------- fp32 -> bf16 weight conversion (6 matrices) ----------------
__global__ __launch_bounds__(256) void conv_kernel(
    const float* __restrict__ wv, const float* __restrict__ w_ih,
    const float* __restrict__ fcW, const float* __restrict__ w_hh,
    const float* __restrict__ Zm, const float* __restrict__ Pm,
    unsigned short* __restrict__ wv_b, unsigned short* __restrict__ wih_b,
    unsigned short* __restrict__ fcw_b, unsigned short* __restrict__ whh_b,
    unsigned short* __restrict__ z_b, unsigned short* __restrict__ p_b)
{
  const long N0 = 2048000, N1 = N0 + 81920, N2 = N1 + 2048000;
  const long N3 = N2 + 81920, N4 = N3 + 16384, N5 = N4 + 16384;
  for (long idx = (long)blockIdx.x * blockDim.x + threadIdx.x; idx < N5;
       idx += (long)gridDim.x * blockDim.x) {
    const float* src; unsigned short* dst; long off;
    if      (idx < N0) { src = wv;   dst = wv_b;  off = idx; }
    else if (idx < N1) { src = w_ih; dst = wih_b; off = idx - N0; }
    else if (idx < N2) { src = fcW;  dst = fcw_b; off = idx - N1; }
    else if (idx < N3) { src = w_hh; dst = whh_b; off = idx - N2; }
    else if (idx < N4) { src = Zm;   dst = z_b;   off = idx - N3; }
    else               { src = Pm;   dst = p_b;   off = idx - N4; }
    float4 v = *(const float4*)(src + off * 4);
    ushort4 o;
    o.x = f2bu(v.x); o.y = f2bu(v.y); o.z = f2bu(v.z); o.w = f2bu(v.w);
    *(ushort4*)(dst + off * 4) = o;
  }
}

// ---------------- per-batch prep: goal embed, ht0, goal_term, E, sumE ----------------
__global__ __launch_bounds__(256) void prep_kernel(
    const int* __restrict__ g, const int* __restrict__ ingr,
    const float* __restrict__ wv, const float* __restrict__ Ug,
    const float* __restrict__ Ym, const float* __restrict__ yb,
    float* __restrict__ E_ws, float* __restrict__ sumE,
    float* __restrict__ goal_ws, float* __restrict__ HT0)
{
  __shared__ float ge[256];
  const int b = blockIdx.x, tid = threadIdx.x;
  float s = 0.f;
  for (int i = 0; i < 8; ++i) s += wv[((size_t)g[(b << 3) + i] << 8) + tid];
  ge[tid] = s;
  __syncthreads();
  float h0 = 0.f, gt = 0.f;
  const float* ur = Ug + (tid << 8);
  const float* yr = Ym + (tid << 8);
#pragma unroll 8
  for (int k = 0; k < Hd; k += 4) {
    float4 gv = *(const float4*)(ge + k);
    float4 uv = *(const float4*)(ur + k);
    float4 yv = *(const float4*)(yr + k);
    h0 = fmaf(gv.x, uv.x, h0); h0 = fmaf(gv.y, uv.y, h0);
    h0 = fmaf(gv.z, uv.z, h0); h0 = fmaf(gv.w, uv.w, h0);
    gt = fmaf(gv.x, yv.x, gt); gt = fmaf(gv.y, yv.y, gt);
    gt = fmaf(gv.z, yv.z, gt); gt = fmaf(gv.w, yv.w, gt);
  }
  HT0[(b << 8) + tid] = h0;                    // [b][c]
  goal_ws[(b << 8) + tid] = gt + yb[tid];      // [b][c]
  float se = 0.f;
  for (int l = 0; l < Ld; ++l) {
    float v = wv[((size_t)ingr[b * Ld + l] << 8) + tid];
    E_ws[((size_t)(b * Ld + l) << 8) + tid] = v;
    se += v;
  }
  sumE[(b << 8) + tid] = se;                   // [b][k]
}

// ---------------- bf16 MFMA GEMM (128x128 tile, K=256), two epilogues ----------------
// MODE 0: gi = gather(wv,recipe) @ w_ih^T + b_ih  ->  gi[b][t][grow] contiguous
// MODE 1: logits = out_all @ fcW^T + fcb          ->  d_out[row][v]
template <int MODE>
__global__ __launch_bounds__(256) void gemm_bf16(
    const unsigned short* __restrict__ A, const unsigned short* __restrict__ Bmat,
    const int* __restrict__ ridx, const float* __restrict__ bias,
    float* __restrict__ C)
{
  __shared__ unsigned short As[128 * 64];
  __shared__ unsigned short Bs[128 * 64];
  const int tid = threadIdx.x;
  const int m0 = blockIdx.x << 7, n0 = blockIdx.y << 7;
  const int wave = tid >> 6, lane = tid & 63;
  const int wm = wave >> 1, wn = wave & 1;
  const int lr = lane & 15, lg = lane >> 4;

  f32x4 acc[4][4];
#pragma unroll
  for (int i = 0; i < 4; ++i)
#pragma unroll
    for (int jj = 0; jj < 4; ++jj) acc[i][jj] = (f32x4){0.f, 0.f, 0.f, 0.f};

  const int srow = tid >> 1, shalf = tid & 1;
  const unsigned short* arow;
  {
    int gm = m0 + srow;
    if (MODE == 0) {
      int tt = gm >> 4, bb = gm & 15;
      arow = A + (size_t)ridx[bb * Td + tt] * Hd;
    } else {
      arow = A + (size_t)gm * Hd;
    }
  }
  const unsigned short* brow = Bmat + (size_t)(n0 + srow) * Hd;

  for (int k0 = 0; k0 < Hd; k0 += 64) {
#pragma unroll
    for (int c = 0; c < 4; ++c) {
      int k = shalf * 32 + c * 8;
      uint4 va = *(const uint4*)(arow + k0 + k);
      uint4 vb = *(const uint4*)(brow + k0 + k);
      int byo = (srow << 7) + ((k << 1) ^ ((srow & 7) << 4));  // XOR swizzle
      *(uint4*)((char*)As + byo) = va;
      *(uint4*)((char*)Bs + byo) = vb;
    }
    __syncthreads();
#pragma unroll
    for (int kk = 0; kk < 2; ++kk) {
      short8v af[4], bfr[4];
      const int kb = kk * 32 + lg * 8;
#pragma unroll
      for (int i = 0; i < 4; ++i) {
        int ar = wm * 64 + i * 16 + lr;
        af[i] = *(const short8v*)((const char*)As + (ar << 7) + ((kb << 1) ^ ((ar & 7) << 4)));
        int br = wn * 64 + i * 16 + lr;
        bfr[i] = *(const short8v*)((const char*)Bs + (br << 7) + ((kb << 1) ^ ((br & 7) << 4)));
      }
#pragma unroll
      for (int i = 0; i < 4; ++i)
#pragma unroll
        for (int jj = 0; jj < 4; ++jj)
          acc[i][jj] = __builtin_amdgcn_mfma_f32_16x16x32_bf16(af[i], bfr[jj], acc[i][jj], 0, 0, 0);
    }
    __syncthreads();
  }
#pragma unroll
  for (int i = 0; i < 4; ++i)
#pragma unroll
    for (int jj = 0; jj < 4; ++jj) {
      int col = n0 + wn * 64 + jj * 16 + lr;
      float bv = bias[col];
#pragma unroll
      for (int r = 0; r < 4; ++r) {
        int row = m0 + wm * 64 + i * 16 + lg * 4 + r;
        float v = acc[i][jj][r] + bv;
        if (MODE == 0) {
          int tt = row >> 4, bb = row & 15;
          C[((size_t)(bb * Td + tt)) * G5H + col] = v;   // gi[b][t][grow]
        } else {
          C[(size_t)row * Vd + col] = v;
        }
      }
    }
}

// ---------------- recurrence kernel v3: one WG per batch, NO grid sync ----------------
// 768 threads (12 waves). Weights streamed bf16 from L2 each step; state in LDS.
// MFMA matrix-vector: B-fragment has only column 0 populated (lanes lane&15==0).
__global__ __launch_bounds__(768, 1) void rnn_kernel(
    const unsigned short* __restrict__ whh_b, const unsigned short* __restrict__ z_b,
    const unsigned short* __restrict__ p_b, const float* __restrict__ b_hh,
    const float* __restrict__ Sm, const float* __restrict__ z_bias,
    const float* __restrict__ gi, const float* __restrict__ goal_ws,
    const float* __restrict__ E_ws, const float* __restrict__ sumE,
    const float* __restrict__ HT0,
    unsigned short* __restrict__ out_all, float* __restrict__ d_out)
{
  __shared__ float gh_lds[1280];
  __shared__ float zd_lds[256];
  __shared__ float hp_lds[256];
  __shared__ float hrow[256];                       // fp32 ht (current)
  __shared__ __align__(16) unsigned short ht_hi[256];
  __shared__ __align__(16) unsigned short ht_lo[256];
  __shared__ __align__(16) unsigned short tp_hi[256];
  __shared__ __align__(16) unsigned short tp_lo[256];
  __shared__ float se_lds[256], gl_lds[256], bh_lds[1280], zb_lds[256];
  __shared__ __align__(16) unsigned short E_lds[Ld * 264];
  __shared__ float a_lds[64], d_lds[64], an_lds[64], au_lds[64];
  __shared__ float sd_lds[4], ref_lds[4];

  const int b = blockIdx.x;
  const int tid = threadIdx.x;
  const int lane = tid & 63, wid = tid >> 6;
  const int lr = lane & 15, lg = lane >> 4;

  // ---- one-time staging ----
  for (int idx = tid; idx < Ld * 256; idx += 768) {
    int l = idx >> 8, k = idx & 255;
    E_lds[l * 264 + k] = f2bu(E_ws[((size_t)(b * Ld + l) << 8) + k]);
  }
  for (int idx = tid; idx < 1280; idx += 768) bh_lds[idx] = b_hh[idx];
  if (tid < 256) {
    float se = sumE[(b << 8) + tid];
    se_lds[tid] = se;
    unsigned short hi = f2bu(se);
    tp_hi[tid] = hi; tp_lo[tid] = f2bu(se - bu2f(hi));
    gl_lds[tid] = goal_ws[(b << 8) + tid];
    zb_lds[tid] = z_bias[tid];
    float h0 = HT0[(b << 8) + tid];
    hrow[tid] = h0;
    unsigned short h0h = f2bu(h0);
    ht_hi[tid] = h0h; ht_lo[tid] = f2bu(h0 - bu2f(h0h));
  }
  if (tid < 64) a_lds[tid] = 0.f;
  __syncthreads();

  for (int t = 0; t < Td; ++t) {
    // ========== phase A: gh (waves 0-9) and zd (waves 10-11) via MFMA ==========
    if (wid < 10) {
      f32x4 acc[8];
#pragma unroll
      for (int i = 0; i < 8; ++i) acc[i] = (f32x4){0.f, 0.f, 0.f, 0.f};
      const unsigned short* wbase = whh_b + (((size_t)(wid * 128 + lr)) << 8) + (lg << 3);
#pragma unroll
      for (int ks = 0; ks < 8; ++ks) {
        short8v bh = {0,0,0,0,0,0,0,0}, bl = {0,0,0,0,0,0,0,0};
        if (lr == 0) {
          bh = *(const short8v*)(ht_hi + ks * 32 + (lg << 3));
          bl = *(const short8v*)(ht_lo + ks * 32 + (lg << 3));
        }
#pragma unroll
        for (int i = 0; i < 8; ++i) {
          short8v a = *(const short8v*)(wbase + (i << 12) + ks * 32);
          acc[i] = __builtin_amdgcn_mfma_f32_16x16x32_bf16(a, bh, acc[i], 0, 0, 0);
          acc[i] = __builtin_amdgcn_mfma_f32_16x16x32_bf16(a, bl, acc[i], 0, 0, 0);
        }
      }
      if (lr == 0) {
#pragma unroll
        for (int i = 0; i < 8; ++i)
#pragma unroll
          for (int r = 0; r < 4; ++r)
            gh_lds[wid * 128 + i * 16 + lg * 4 + r] = acc[i][r];
      }
    } else {
      const int zt0 = (wid - 10) * 8;              // tile base (16 Z tiles total)
      f32x4 acc[8];
#pragma unroll
      for (int i = 0; i < 8; ++i) acc[i] = (f32x4){0.f, 0.f, 0.f, 0.f};
      const unsigned short* wbase = z_b + (((size_t)(zt0 * 16 + lr)) << 8) + (lg << 3);
#pragma unroll
      for (int ks = 0; ks < 8; ++ks) {
        short8v bh = {0,0,0,0,0,0,0,0}, bl = {0,0,0,0,0,0,0,0};
        if (lr == 0) {
          bh = *(const short8v*)(tp_hi + ks * 32 + (lg << 3));
          bl = *(const short8v*)(tp_lo + ks * 32 + (lg << 3));
        }
#pragma unroll
        for (int i = 0; i < 8; ++i) {
          short8v a = *(const short8v*)(wbase + (i << 12) + ks * 32);
          acc[i] = __builtin_amdgcn_mfma_f32_16x16x32_bf16(a, bh, acc[i], 0, 0, 0);
          acc[i] = __builtin_amdgcn_mfma_f32_16x16x32_bf16(a, bl, acc[i], 0, 0, 0);
        }
      }
      if (lr == 0) {
#pragma unroll
        for (int i = 0; i < 8; ++i)
#pragma unroll
          for (int r = 0; r < 4; ++r)
            zd_lds[(zt0 + i) * 16 + lg * 4 + r] = acc[i][r];
      }
    }
    __syncthreads();
    // ========== phase B: gates -> ht2 ==========
    if (tid < 256) {
      int c = tid;
      const float* gib = gi + ((size_t)(b * Td + t)) * G5H;
      float i_r = gib[c], i_u = gib[256 + c], i_n = gib[512 + c];
      float i_g = gib[768 + c], i_i = gib[1024 + c];
      float hr = gh_lds[c]        + bh_lds[c];
      float hu = gh_lds[256 + c]  + bh_lds[256 + c];
      float hn = gh_lds[512 + c]  + bh_lds[512 + c];
      float hg = gh_lds[768 + c]  + bh_lds[768 + c];
      float hq = gh_lds[1024 + c] + bh_lds[1024 + c];
      float rt = sigm(i_r + hr), zt = sigm(i_u + hu);
      float st = sigm(i_g + hg), qt = sigm(i_i + hq);
      float htl = tanhf(i_n + rt * hn + st * gl_lds[c] + qt * (zd_lds[c] + zb_lds[c]));
      float prev = hrow[c];
      float h2 = htl + zt * (prev - htl);
      hrow[c] = h2;
      unsigned short hi = f2bu(h2);
      ht_hi[c] = hi; ht_lo[c] = f2bu(h2 - bu2f(hi));
    }
    __syncthreads();
    // ========== phase C: h_proj (waves 0-7) + S-dots (waves 8-10) ==========
    if (wid < 8) {
      f32x4 acc[2];
      acc[0] = (f32x4){0.f, 0.f, 0.f, 0.f};
      acc[1] = (f32x4){0.f, 0.f, 0.f, 0.f};
      const unsigned short* pbase = p_b + (((size_t)(wid * 32 + lr)) << 8) + (lg << 3);
#pragma unroll
      for (int ks = 0; ks < 8; ++ks) {
        short8v bh = {0,0,0,0,0,0,0,0}, bl = {0,0,0,0,0,0,0,0};
        if (lr == 0) {
          bh = *(const short8v*)(ht_hi + ks * 32 + (lg << 3));
          bl = *(const short8v*)(ht_lo + ks * 32 + (lg << 3));
        }
#pragma unroll
        for (int i = 0; i < 2; ++i) {
          short8v a = *(const short8v*)(pbase + (i << 12) + ks * 32);
          acc[i] = __builtin_amdgcn_mfma_f32_16x16x32_bf16(a, bh, acc[i], 0, 0, 0);
          acc[i] = __builtin_amdgcn_mfma_f32_16x16x32_bf16(a, bl, acc[i], 0, 0, 0);
        }
      }
      if (lr == 0) {
#pragma unroll
        for (int i = 0; i < 2; ++i)
#pragma unroll
          for (int r = 0; r < 4; ++r)
            hp_lds[wid * 32 + i * 16 + lg * 4 + r] = acc[i][r];
      }
    } else if (wid < 11) {                          // S dots
      int w = wid - 8;
      float4 sv = *(const float4*)(Sm + (w << 8) + (lane << 2));
      float4 hv = *(const float4*)(hrow + (lane << 2));
      float p = sv.x * hv.x + sv.y * hv.y + sv.z * hv.z + sv.w * hv.w;
      p += __shfl_xor(p, 1);  p += __shfl_xor(p, 2);  p += __shfl_xor(p, 4);
      p += __shfl_xor(p, 8);  p += __shfl_xor(p, 16); p += __shfl_xor(p, 32);
      if (lane == 0) sd_lds[w] = p;
    }
    __syncthreads();
    // ========== phase D: E-dots + ref softmax ==========
    if (tid < 200) {
      int l = tid >> 2, q = tid & 3;
      const unsigned short* er = E_lds + l * 264 + (q << 6);
      const float* hq = hp_lds + (q << 6);
      float p = 0.f;
#pragma unroll 8
      for (int i = 0; i < 32; ++i) {
        unsigned uu = *(const unsigned*)(er + 2 * i);
        float e0 = __uint_as_float(uu << 16);
        float e1 = __uint_as_float(uu & 0xffff0000u);
        p = fmaf(e0, hq[2 * i], p);
        p = fmaf(e1, hq[2 * i + 1], p);
      }
      p += __shfl_xor(p, 1); p += __shfl_xor(p, 2);
      if (q == 0) d_lds[l] = p;
    } else if (tid == 704) {                        // ref = softmax(BETA*sd)
      float s0 = 5.0f * sd_lds[0], s1 = 5.0f * sd_lds[1], s2 = 5.0f * sd_lds[2];
      float m = fmaxf(s0, fmaxf(s1, s2));
      float e0 = __expf(s0 - m), e1 = __expf(s1 - m), e2 = __expf(s2 - m);
      float inv = 1.f / (e0 + e1 + e2);
      ref_lds[0] = e0 * inv; ref_lds[1] = e1 * inv; ref_lds[2] = e2 * inv;
    }
    __syncthreads();
    // ========== phase E: alpha_n / alpha_u ==========
    if (tid < 128) {
      int which = tid >> 6;
      int l = tid & 63;
      float dv;
      if (which == 0) dv = (l < Ld) ? 2.0f * (1.f - a_lds[l]) * d_lds[l] : -3.4e38f;
      else            dv = (l < Ld) ? 2.0f * a_lds[l] * d_lds[l]         : -3.4e38f;
      float m = dv;
      m = fmaxf(m, __shfl_xor(m, 1));  m = fmaxf(m, __shfl_xor(m, 2));
      m = fmaxf(m, __shfl_xor(m, 4));  m = fmaxf(m, __shfl_xor(m, 8));
      m = fmaxf(m, __shfl_xor(m, 16)); m = fmaxf(m, __shfl_xor(m, 32));
      float e = (l < Ld) ? __expf(dv - m) : 0.f;
      float ss = e;
      ss += __shfl_xor(ss, 1);  ss += __shfl_xor(ss, 2);  ss += __shfl_xor(ss, 4);
      ss += __shfl_xor(ss, 8);  ss += __shfl_xor(ss, 16); ss += __shfl_xor(ss, 32);
      float al = e / ss;
      if (which == 0) an_lds[l] = al; else au_lds[l] = al;
    }
    __syncthreads();
    // ========== phase F: c_n, c_u, out, tmp(t+1) ==========
    if (tid < 256) {
      int k = tid;
      float accn = 0.f, accu = 0.f, acct = 0.f;
#pragma unroll 10
      for (int l = 0; l < Ld; ++l) {
        float e = bu2f(E_lds[l * 264 + k]);
        accn = fmaf(an_lds[l], e, accn);
        accu = fmaf(au_lds[l], e, accu);
        acct = fmaf(a_lds[l], e, acct);            // a BEFORE this step's update
      }
      float outv = ref_lds[0] * hp_lds[k] + ref_lds[1] * accn + ref_lds[2] * accu;
      out_all[(((b << 7) + t) << 8) + k] = f2bu(outv);
      float tn = se_lds[k] - acct;                 // tmp(t+1) = sum((1-a)*E)
      unsigned short th = f2bu(tn);
      tp_hi[k] = th; tp_lo[k] = f2bu(tn - bu2f(th));
      if (t == Td - 1) {
        d_out[(size_t)65536000 + (b << 8) + k] = hrow[k];
        for (int l = 0; l < Ld; ++l) {             // E_new = (1-a_pre)*E (fp32 source)
          size_t o = ((size_t)(b * Ld + l) << 8) + k;
          d_out[(size_t)65540896 + o] = (1.f - a_lds[l]) * E_ws[o];
        }
      }
    }
    __syncthreads();
    // ========== phase G: a update ==========
    if (tid < Ld) {
      float na = a_lds[tid] + ref_lds[1] * an_lds[tid];
      a_lds[tid] = na;
      if (t == Td - 1) d_out[(size_t)65540096 + b * Ld + tid] = na;
    }
    __syncthreads();
  }
}

// ---------------- host launcher ----------------
extern "C" void kernel_launch(void* const* d_in, const int* in_sizes, int n_in,
                              void* d_out, int out_size, void* d_ws, size_t ws_size,
                              hipStream_t stream)
{
  const int*   recipe = (const int*)d_in[0];
  const int*   g      = (const int*)d_in[1];
  const int*   ingr   = (const int*)d_in[2];
  const float* wv     = (const float*)d_in[3];
  const float* w_ih   = (const float*)d_in[4];
  const float* w_hh   = (const float*)d_in[5];
  const float* b_ih   = (const float*)d_in[6];
  const float* b_hh   = (const float*)d_in[7];
  const float* Z      = (const float*)d_in[8];
  const float* Y      = (const float*)d_in[9];
  const float* Ug     = (const float*)d_in[10];
  const float* z_bias = (const float*)d_in[11];
  const float* y_bias = (const float*)d_in[12];
  const float* S      = (const float*)d_in[13];
  const float* P      = (const float*)d_in[14];
  const float* fcW    = (const float*)d_in[15];
  const float* fcb    = (const float*)d_in[16];
  float* out = (float*)d_out;
  char* ws = (char*)d_ws;

  size_t off = 0;
  unsigned short* wv_b     = (unsigned short*)(ws + off);  off += 16384000;
  unsigned short* wih_b    = (unsigned short*)(ws + off);  off += 655360;
  unsigned short* fcw_b    = (unsigned short*)(ws + off);  off += 16384000;
  unsigned short* whh_b    = (unsigned short*)(ws + off);  off += 655360;
  unsigned short* z_b      = (unsigned short*)(ws + off);  off += 131072;
  unsigned short* p_b      = (unsigned short*)(ws + off);  off += 131072;
  float* gi_ws             = (float*)(ws + off);           off += 10485760;
  float* E_ws              = (float*)(ws + off);           off += 819200;
  float* sumE              = (float*)(ws + off);           off += 16384;
  float* goal_ws           = (float*)(ws + off);           off += 16384;
  float* HT0               = (float*)(ws + off);           off += 16384;
  unsigned short* out_all  = (unsigned short*)(ws + off);  off += 1048576;

  conv_kernel<<<4096, 256, 0, stream>>>(wv, w_ih, fcW, w_hh, Z, P,
                                        wv_b, wih_b, fcw_b, whh_b, z_b, p_b);
  prep_kernel<<<16, 256, 0, stream>>>(g, ingr, wv, Ug, Y, y_bias,
                                      E_ws, sumE, goal_ws, HT0);
  gemm_bf16<0><<<dim3(16, 10), 256, 0, stream>>>(wv_b, wih_b, recipe, b_ih, gi_ws);
  rnn_kernel<<<16, 768, 0, stream>>>(whh_b, z_b, p_b, b_hh, S, z_bias,
                                     gi_ws, goal_ws, E_ws, sumE, HT0,
                                     out_all, out);
  gemm_bf16<1><<<dim3(16, 250), 256, 0, stream>>>(out_all, fcw_b, nullptr, fcb, out);
}

// Round 4
// 3331.181 us; speedup vs baseline: 1.4396x; 1.4396x over previous
//
#include <hip/hip_runtime.h>

// ---------------- problem constants ----------------
#define Hd   256
#define Bd   16
#define Td   128
#define Ld   50
#define Vd   32000
#define G5H  1280     // 5*H

typedef __attribute__((ext_vector_type(8))) short short8v;  // 8 bf16 (4 VGPRs)
typedef __attribute__((ext_vector_type(4))) float f32x4;

__device__ __forceinline__ unsigned short f2bu(float f) {   // f32 -> bf16 bits (RNE)
  unsigned u = __float_as_uint(f);
  unsigned r = (u + 0x7fffu + ((u >> 16) & 1u)) >> 16;
  return (unsigned short)r;
}
__device__ __forceinline__ float bu2f(unsigned short b) {
  return __uint_as_float(((unsigned)b) << 16);
}
__device__ __forceinline__ float sigm(float x) { return 1.f / (1.f + __expf(-x)); }

// ---------------- fp32 -> bf16 conversion + MFMA fragment packing ----------------
// Plain bf16 copies: wv, w_ih, fcW (row-major, used by LDS-staged GEMMs).
// Fragment-ordered bf16: w_hh, Z, P. Fragment (T,ks) = 512 shorts laid out so
// lane L of a wave reads shorts [frag*512 + L*8 .. +8) = mat[T*16 + (L&15)]
// [ks*32 + (L>>4)*8 .. +8)  -> every A-load is one coalesced 1KB stream.
__global__ __launch_bounds__(256) void conv_kernel(
    const float* __restrict__ wv, const float* __restrict__ w_ih,
    const float* __restrict__ fcW, const float* __restrict__ w_hh,
    const float* __restrict__ Zm, const float* __restrict__ Pm,
    unsigned short* __restrict__ wv_b, unsigned short* __restrict__ wih_b,
    unsigned short* __restrict__ fcw_b, unsigned short* __restrict__ whh_f,
    unsigned short* __restrict__ z_f, unsigned short* __restrict__ p_f)
{
  const long N0 = 2048000, N1 = N0 + 81920, N2 = N1 + 2048000;
  const long NW = 81920, NZ = 16384, NP = 16384;         // frag float4-groups
  const long N5 = N2 + NW + NZ + NP;
  for (long idx = (long)blockIdx.x * blockDim.x + threadIdx.x; idx < N5;
       idx += (long)gridDim.x * blockDim.x) {
    if (idx < N2) {                                      // plain copies
      const float* src; unsigned short* dst; long off;
      if      (idx < N0) { src = wv;   dst = wv_b;  off = idx; }
      else if (idx < N1) { src = w_ih; dst = wih_b; off = idx - N0; }
      else               { src = fcW;  dst = fcw_b; off = idx - N1; }
      float4 v = *(const float4*)(src + off * 4);
      ushort4 o;
      o.x = f2bu(v.x); o.y = f2bu(v.y); o.z = f2bu(v.z); o.w = f2bu(v.w);
      *(ushort4*)(dst + off * 4) = o;
    } else {                                             // fragment packing
      long u = idx - N2;
      const float* src; unsigned short* dst;
      if      (u < NW)      { src = w_hh; dst = whh_f; }
      else if (u < NW + NZ) { src = Zm;   dst = z_f;  u -= NW; }
      else                  { src = Pm;   dst = p_f;  u -= NW + NZ; }
      long frag = u >> 7;                 // 128 float4-groups per 512-short frag
      int g128 = (int)(u & 127);
      int lane = g128 >> 1, e0 = (g128 & 1) * 4;
      long T = frag >> 3; int ks = (int)(frag & 7);
      int lr = lane & 15, lg = lane >> 4;
      float4 v = *(const float4*)(src + (T * 16 + lr) * 256 + ks * 32 + lg * 8 + e0);
      ushort4 o;
      o.x = f2bu(v.x); o.y = f2bu(v.y); o.z = f2bu(v.z); o.w = f2bu(v.w);
      *(ushort4*)(dst + u * 4) = o;
    }
  }
}

// ---------------- per-batch prep: goal embed, ht0, goal_term, E, sumE ----------------
__global__ __launch_bounds__(256) void prep_kernel(
    const int* __restrict__ g, const int* __restrict__ ingr,
    const float* __restrict__ wv, const float* __restrict__ Ug,
    const float* __restrict__ Ym, const float* __restrict__ yb,
    float* __restrict__ E_ws, float* __restrict__ sumE,
    float* __restrict__ goal_ws, float* __restrict__ HT0)
{
  __shared__ float ge[256];
  const int b = blockIdx.x, tid = threadIdx.x;
  float s = 0.f;
  for (int i = 0; i < 8; ++i) s += wv[((size_t)g[(b << 3) + i] << 8) + tid];
  ge[tid] = s;
  __syncthreads();
  float h0 = 0.f, gt = 0.f;
  const float* ur = Ug + (tid << 8);
  const float* yr = Ym + (tid << 8);
#pragma unroll 8
  for (int k = 0; k < Hd; k += 4) {
    float4 gv = *(const float4*)(ge + k);
    float4 uv = *(const float4*)(ur + k);
    float4 yv = *(const float4*)(yr + k);
    h0 = fmaf(gv.x, uv.x, h0); h0 = fmaf(gv.y, uv.y, h0);
    h0 = fmaf(gv.z, uv.z, h0); h0 = fmaf(gv.w, uv.w, h0);
    gt = fmaf(gv.x, yv.x, gt); gt = fmaf(gv.y, yv.y, gt);
    gt = fmaf(gv.z, yv.z, gt); gt = fmaf(gv.w, yv.w, gt);
  }
  HT0[(b << 8) + tid] = h0;                    // [b][c]
  goal_ws[(b << 8) + tid] = gt + yb[tid];      // [b][c]
  float se = 0.f;
  for (int l = 0; l < Ld; ++l) {
    float v = wv[((size_t)ingr[b * Ld + l] << 8) + tid];
    E_ws[((size_t)(b * Ld + l) << 8) + tid] = v;
    se += v;
  }
  sumE[(b << 8) + tid] = se;                   // [b][k]
}

// ---------------- bf16 MFMA GEMM (128x128 tile, K=256), two epilogues ----------------
template <int MODE>
__global__ __launch_bounds__(256) void gemm_bf16(
    const unsigned short* __restrict__ A, const unsigned short* __restrict__ Bmat,
    const int* __restrict__ ridx, const float* __restrict__ bias,
    float* __restrict__ C)
{
  __shared__ unsigned short As[128 * 64];
  __shared__ unsigned short Bs[128 * 64];
  const int tid = threadIdx.x;
  const int m0 = blockIdx.x << 7, n0 = blockIdx.y << 7;
  const int wave = tid >> 6, lane = tid & 63;
  const int wm = wave >> 1, wn = wave & 1;
  const int lr = lane & 15, lg = lane >> 4;

  f32x4 acc[4][4];
#pragma unroll
  for (int i = 0; i < 4; ++i)
#pragma unroll
    for (int jj = 0; jj < 4; ++jj) acc[i][jj] = (f32x4){0.f, 0.f, 0.f, 0.f};

  const int srow = tid >> 1, shalf = tid & 1;
  const unsigned short* arow;
  {
    int gm = m0 + srow;
    if (MODE == 0) {
      int tt = gm >> 4, bb = gm & 15;
      arow = A + (size_t)ridx[bb * Td + tt] * Hd;
    } else {
      arow = A + (size_t)gm * Hd;
    }
  }
  const unsigned short* brow = Bmat + (size_t)(n0 + srow) * Hd;

  for (int k0 = 0; k0 < Hd; k0 += 64) {
#pragma unroll
    for (int c = 0; c < 4; ++c) {
      int k = shalf * 32 + c * 8;
      uint4 va = *(const uint4*)(arow + k0 + k);
      uint4 vb = *(const uint4*)(brow + k0 + k);
      int byo = (srow << 7) + ((k << 1) ^ ((srow & 7) << 4));  // XOR swizzle
      *(uint4*)((char*)As + byo) = va;
      *(uint4*)((char*)Bs + byo) = vb;
    }
    __syncthreads();
#pragma unroll
    for (int kk = 0; kk < 2; ++kk) {
      short8v af[4], bfr[4];
      const int kb = kk * 32 + lg * 8;
#pragma unroll
      for (int i = 0; i < 4; ++i) {
        int ar = wm * 64 + i * 16 + lr;
        af[i] = *(const short8v*)((const char*)As + (ar << 7) + ((kb << 1) ^ ((ar & 7) << 4)));
        int br = wn * 64 + i * 16 + lr;
        bfr[i] = *(const short8v*)((const char*)Bs + (br << 7) + ((kb << 1) ^ ((br & 7) << 4)));
      }
#pragma unroll
      for (int i = 0; i < 4; ++i)
#pragma unroll
        for (int jj = 0; jj < 4; ++jj)
          acc[i][jj] = __builtin_amdgcn_mfma_f32_16x16x32_bf16(af[i], bfr[jj], acc[i][jj], 0, 0, 0);
    }
    __syncthreads();
  }
#pragma unroll
  for (int i = 0; i < 4; ++i)
#pragma unroll
    for (int jj = 0; jj < 4; ++jj) {
      int col = n0 + wn * 64 + jj * 16 + lr;
      float bv = bias[col];
#pragma unroll
      for (int r = 0; r < 4; ++r) {
        int row = m0 + wm * 64 + i * 16 + lg * 4 + r;
        float v = acc[i][jj][r] + bv;
        if (MODE == 0) {
          int tt = row >> 4, bb = row & 15;
          C[((size_t)(bb * Td + tt)) * G5H + col] = v;   // gi[b][t][grow]
        } else {
          C[(size_t)row * Vd + col] = v;
        }
      }
    }
}

// ---------------- recurrence kernel v4: one WG per batch, frag-ordered streams ----------------
__global__ __launch_bounds__(768, 1) void rnn_kernel(
    const unsigned short* __restrict__ whh_f, const unsigned short* __restrict__ z_f,
    const unsigned short* __restrict__ p_f, const float* __restrict__ b_hh,
    const float* __restrict__ Sm, const float* __restrict__ z_bias,
    const float* __restrict__ gi, const float* __restrict__ goal_ws,
    const float* __restrict__ E_ws, const float* __restrict__ sumE,
    const float* __restrict__ HT0,
    unsigned short* __restrict__ out_all, float* __restrict__ d_out)
{
  __shared__ float gh_lds[1280];
  __shared__ float zd_lds[256];
  __shared__ float hp_lds[256];
  __shared__ float hrow[256];                       // fp32 ht (current)
  __shared__ __align__(16) unsigned short ht_hi[256];
  __shared__ __align__(16) unsigned short ht_lo[256];
  __shared__ __align__(16) unsigned short tp_hi[256];
  __shared__ __align__(16) unsigned short tp_lo[256];
  __shared__ float se_lds[256], gl_lds[256], bh_lds[1280], zb_lds[256];
  __shared__ __align__(16) unsigned short E_lds[Ld * 264];
  __shared__ float a_lds[64], d_lds[64], an_lds[64], au_lds[64];
  __shared__ float sd_lds[4], ref_lds[4];

  const int b = blockIdx.x;
  const int tid = threadIdx.x;
  const int lane = tid & 63, wid = tid >> 6;
  const int lr = lane & 15, lg = lane >> 4;

  // ---- one-time staging ----
  for (int idx = tid; idx < Ld * 256; idx += 768) {
    int l = idx >> 8, k = idx & 255;
    E_lds[l * 264 + k] = f2bu(E_ws[((size_t)(b * Ld + l) << 8) + k]);
  }
  for (int idx = tid; idx < 1280; idx += 768) bh_lds[idx] = b_hh[idx];
  if (tid < 256) {
    float se = sumE[(b << 8) + tid];
    se_lds[tid] = se;
    unsigned short hi = f2bu(se);
    tp_hi[tid] = hi; tp_lo[tid] = f2bu(se - bu2f(hi));
    gl_lds[tid] = goal_ws[(b << 8) + tid];
    zb_lds[tid] = z_bias[tid];
    float h0 = HT0[(b << 8) + tid];
    hrow[tid] = h0;
    unsigned short h0h = f2bu(h0);
    ht_hi[tid] = h0h; ht_lo[tid] = f2bu(h0 - bu2f(h0h));
  }
  if (tid < 64) a_lds[tid] = 0.f;
  __syncthreads();

  for (int t = 0; t < Td; ++t) {
    // ---- prefetch gi(t) early: latency hides under phase A ----
    float pre_ir = 0.f, pre_iu = 0.f, pre_in = 0.f, pre_ig = 0.f, pre_ii = 0.f;
    if (tid < 256) {
      const float* gib = gi + ((size_t)(b * Td + t)) * G5H + tid;
      pre_ir = gib[0];    pre_iu = gib[256];  pre_in = gib[512];
      pre_ig = gib[768];  pre_ii = gib[1024];
    }
    // ========== phase A: gh (waves 0-9) and zd (waves 10-11) via MFMA ==========
    if (wid < 10) {
      f32x4 acc[8];
#pragma unroll
      for (int i = 0; i < 8; ++i) acc[i] = (f32x4){0.f, 0.f, 0.f, 0.f};
      const unsigned short* fb = whh_f + (((size_t)wid * 64) << 9) + (lane << 3);
      short8v aA[8], aB[8];
#pragma unroll
      for (int i = 0; i < 8; ++i) aA[i] = *(const short8v*)(fb + ((i * 8) << 9));
#define GH_KS(CUR, NXT, KS)                                                    \
      {                                                                        \
        if ((KS) < 7) {                                                        \
          _Pragma("unroll")                                                    \
          for (int i = 0; i < 8; ++i)                                          \
            NXT[i] = *(const short8v*)(fb + ((i * 8 + (KS) + 1) << 9));        \
        }                                                                      \
        short8v bh = {0,0,0,0,0,0,0,0}, bl = {0,0,0,0,0,0,0,0};                \
        if (lr == 0) {                                                         \
          bh = *(const short8v*)(ht_hi + (KS) * 32 + (lg << 3));               \
          bl = *(const short8v*)(ht_lo + (KS) * 32 + (lg << 3));               \
        }                                                                      \
        _Pragma("unroll")                                                      \
        for (int i = 0; i < 8; ++i) {                                          \
          acc[i] = __builtin_amdgcn_mfma_f32_16x16x32_bf16(CUR[i], bh, acc[i], 0, 0, 0); \
          acc[i] = __builtin_amdgcn_mfma_f32_16x16x32_bf16(CUR[i], bl, acc[i], 0, 0, 0); \
        }                                                                      \
      }
      GH_KS(aA, aB, 0) GH_KS(aB, aA, 1) GH_KS(aA, aB, 2) GH_KS(aB, aA, 3)
      GH_KS(aA, aB, 4) GH_KS(aB, aA, 5) GH_KS(aA, aB, 6) GH_KS(aB, aA, 7)
#undef GH_KS
      if (lr == 0) {
#pragma unroll
        for (int i = 0; i < 8; ++i)
#pragma unroll
          for (int r = 0; r < 4; ++r)
            gh_lds[wid * 128 + i * 16 + lg * 4 + r] = acc[i][r];
      }
    } else {
      const int zw = wid - 10;                       // 0 or 1; 8 Z tiles each
      f32x4 acc[8];
#pragma unroll
      for (int i = 0; i < 8; ++i) acc[i] = (f32x4){0.f, 0.f, 0.f, 0.f};
      const unsigned short* fb = z_f + (((size_t)zw * 64) << 9) + (lane << 3);
      short8v aA[8], aB[8];
#pragma unroll
      for (int i = 0; i < 8; ++i) aA[i] = *(const short8v*)(fb + ((i * 8) << 9));
#define ZD_KS(CUR, NXT, KS)                                                    \
      {                                                                        \
        if ((KS) < 7) {                                                        \
          _Pragma("unroll")                                                    \
          for (int i = 0; i < 8; ++i)                                          \
            NXT[i] = *(const short8v*)(fb + ((i * 8 + (KS) + 1) << 9));        \
        }                                                                      \
        short8v bh = {0,0,0,0,0,0,0,0}, bl = {0,0,0,0,0,0,0,0};                \
        if (lr == 0) {                                                         \
          bh = *(const short8v*)(tp_hi + (KS) * 32 + (lg << 3));               \
          bl = *(const short8v*)(tp_lo + (KS) * 32 + (lg << 3));               \
        }                                                                      \
        _Pragma("unroll")                                                      \
        for (int i = 0; i < 8; ++i) {                                          \
          acc[i] = __builtin_amdgcn_mfma_f32_16x16x32_bf16(CUR[i], bh, acc[i], 0, 0, 0); \
          acc[i] = __builtin_amdgcn_mfma_f32_16x16x32_bf16(CUR[i], bl, acc[i], 0, 0, 0); \
        }                                                                      \
      }
      ZD_KS(aA, aB, 0) ZD_KS(aB, aA, 1) ZD_KS(aA, aB, 2) ZD_KS(aB, aA, 3)
      ZD_KS(aA, aB, 4) ZD_KS(aB, aA, 5) ZD_KS(aA, aB, 6) ZD_KS(aB, aA, 7)
#undef ZD_KS
      if (lr == 0) {
#pragma unroll
        for (int i = 0; i < 8; ++i)
#pragma unroll
          for (int r = 0; r < 4; ++r)
            zd_lds[(zw * 8 + i) * 16 + lg * 4 + r] = acc[i][r];
      }
    }
    __syncthreads();
    // ========== phase B: gates -> ht2 ==========
    if (tid < 256) {
      int c = tid;
      float hr = gh_lds[c]        + bh_lds[c];
      float hu = gh_lds[256 + c]  + bh_lds[256 + c];
      float hn = gh_lds[512 + c]  + bh_lds[512 + c];
      float hg = gh_lds[768 + c]  + bh_lds[768 + c];
      float hq = gh_lds[1024 + c] + bh_lds[1024 + c];
      float rt = sigm(pre_ir + hr), zt = sigm(pre_iu + hu);
      float st = sigm(pre_ig + hg), qt = sigm(pre_ii + hq);
      float htl = tanhf(pre_in + rt * hn + st * gl_lds[c] + qt * (zd_lds[c] + zb_lds[c]));
      float prev = hrow[c];
      float h2 = htl + zt * (prev - htl);
      hrow[c] = h2;
      unsigned short hi = f2bu(h2);
      ht_hi[c] = hi; ht_lo[c] = f2bu(h2 - bu2f(hi));
    }
    __syncthreads();
    // ========== phase C: h_proj (waves 0-7) + S-dots (waves 8-10) ==========
    if (wid < 8) {
      f32x4 acc[2];
      acc[0] = (f32x4){0.f, 0.f, 0.f, 0.f};
      acc[1] = (f32x4){0.f, 0.f, 0.f, 0.f};
      const unsigned short* fb = p_f + (((size_t)wid * 16) << 9) + (lane << 3);
      short8v aA[2], aB[2];
#pragma unroll
      for (int i = 0; i < 2; ++i) aA[i] = *(const short8v*)(fb + ((i * 8) << 9));
#define HP_KS(CUR, NXT, KS)                                                    \
      {                                                                        \
        if ((KS) < 7) {                                                        \
          _Pragma("unroll")                                                    \
          for (int i = 0; i < 2; ++i)                                          \
            NXT[i] = *(const short8v*)(fb + ((i * 8 + (KS) + 1) << 9));        \
        }                                                                      \
        short8v bh = {0,0,0,0,0,0,0,0}, bl = {0,0,0,0,0,0,0,0};                \
        if (lr == 0) {                                                         \
          bh = *(const short8v*)(ht_hi + (KS) * 32 + (lg << 3));               \
          bl = *(const short8v*)(ht_lo + (KS) * 32 + (lg << 3));               \
        }                                                                      \
        _Pragma("unroll")                                                      \
        for (int i = 0; i < 2; ++i) {                                          \
          acc[i] = __builtin_amdgcn_mfma_f32_16x16x32_bf16(CUR[i], bh, acc[i], 0, 0, 0); \
          acc[i] = __builtin_amdgcn_mfma_f32_16x16x32_bf16(CUR[i], bl, acc[i], 0, 0, 0); \
        }                                                                      \
      }
      HP_KS(aA, aB, 0) HP_KS(aB, aA, 1) HP_KS(aA, aB, 2) HP_KS(aB, aA, 3)
      HP_KS(aA, aB, 4) HP_KS(aB, aA, 5) HP_KS(aA, aB, 6) HP_KS(aB, aA, 7)
#undef HP_KS
      if (lr == 0) {
#pragma unroll
        for (int i = 0; i < 2; ++i)
#pragma unroll
          for (int r = 0; r < 4; ++r)
            hp_lds[wid * 32 + i * 16 + lg * 4 + r] = acc[i][r];
      }
    } else if (wid < 11) {                          // S dots
      int w = wid - 8;
      float4 sv = *(const float4*)(Sm + (w << 8) + (lane << 2));
      float4 hv = *(const float4*)(hrow + (lane << 2));
      float p = sv.x * hv.x + sv.y * hv.y + sv.z * hv.z + sv.w * hv.w;
      p += __shfl_xor(p, 1);  p += __shfl_xor(p, 2);  p += __shfl_xor(p, 4);
      p += __shfl_xor(p, 8);  p += __shfl_xor(p, 16); p += __shfl_xor(p, 32);
      if (lane == 0) sd_lds[w] = p;
    }
    __syncthreads();
    // ========== phase D: E-dots + ref softmax ==========
    if (tid < 200) {
      int l = tid >> 2, q = tid & 3;
      const unsigned short* er = E_lds + l * 264 + (q << 6);
      const float* hq = hp_lds + (q << 6);
      float p = 0.f;
#pragma unroll 8
      for (int i = 0; i < 32; ++i) {
        unsigned uu = *(const unsigned*)(er + 2 * i);
        float e0 = __uint_as_float(uu << 16);
        float e1 = __uint_as_float(uu & 0xffff0000u);
        p = fmaf(e0, hq[2 * i], p);
        p = fmaf(e1, hq[2 * i + 1], p);
      }
      p += __shfl_xor(p, 1); p += __shfl_xor(p, 2);
      if (q == 0) d_lds[l] = p;
    } else if (tid == 704) {                        // ref = softmax(BETA*sd)
      float s0 = 5.0f * sd_lds[0], s1 = 5.0f * sd_lds[1], s2 = 5.0f * sd_lds[2];
      float m = fmaxf(s0, fmaxf(s1, s2));
      float e0 = __expf(s0 - m), e1 = __expf(s1 - m), e2 = __expf(s2 - m);
      float inv = 1.f / (e0 + e1 + e2);
      ref_lds[0] = e0 * inv; ref_lds[1] = e1 * inv; ref_lds[2] = e2 * inv;
    }
    __syncthreads();
    // ========== phase E: alpha_n / alpha_u ==========
    if (tid < 128) {
      int which = tid >> 6;
      int l = tid & 63;
      float dv;
      if (which == 0) dv = (l < Ld) ? 2.0f * (1.f - a_lds[l]) * d_lds[l] : -3.4e38f;
      else            dv = (l < Ld) ? 2.0f * a_lds[l] * d_lds[l]         : -3.4e38f;
      float m = dv;
      m = fmaxf(m, __shfl_xor(m, 1));  m = fmaxf(m, __shfl_xor(m, 2));
      m = fmaxf(m, __shfl_xor(m, 4));  m = fmaxf(m, __shfl_xor(m, 8));
      m = fmaxf(m, __shfl_xor(m, 16)); m = fmaxf(m, __shfl_xor(m, 32));
      float e = (l < Ld) ? __expf(dv - m) : 0.f;
      float ss = e;
      ss += __shfl_xor(ss, 1);  ss += __shfl_xor(ss, 2);  ss += __shfl_xor(ss, 4);
      ss += __shfl_xor(ss, 8);  ss += __shfl_xor(ss, 16); ss += __shfl_xor(ss, 32);
      float al = e / ss;
      if (which == 0) an_lds[l] = al; else au_lds[l] = al;
    }
    __syncthreads();
    // ========== phase F: c_n, c_u, out, tmp(t+1) ==========
    if (tid < 256) {
      int k = tid;
      float accn = 0.f, accu = 0.f, acct = 0.f;
#pragma unroll 10
      for (int l = 0; l < Ld; ++l) {
        float e = bu2f(E_lds[l * 264 + k]);
        accn = fmaf(an_lds[l], e, accn);
        accu = fmaf(au_lds[l], e, accu);
        acct = fmaf(a_lds[l], e, acct);            // a BEFORE this step's update
      }
      float outv = ref_lds[0] * hp_lds[k] + ref_lds[1] * accn + ref_lds[2] * accu;
      out_all[(((b << 7) + t) << 8) + k] = f2bu(outv);
      float tn = se_lds[k] - acct;                 // tmp(t+1) = sum((1-a)*E)
      unsigned short th = f2bu(tn);
      tp_hi[k] = th; tp_lo[k] = f2bu(tn - bu2f(th));
      if (t == Td - 1) {
        d_out[(size_t)65536000 + (b << 8) + k] = hrow[k];
        for (int l = 0; l < Ld; ++l) {             // E_new = (1-a_pre)*E (fp32 source)
          size_t o = ((size_t)(b * Ld + l) << 8) + k;
          d_out[(size_t)65540896 + o] = (1.f - a_lds[l]) * E_ws[o];
        }
      }
    }
    __syncthreads();
    // ========== phase G: a update ==========
    if (tid < Ld) {
      float na = a_lds[tid] + ref_lds[1] * an_lds[tid];
      a_lds[tid] = na;
      if (t == Td - 1) d_out[(size_t)65540096 + b * Ld + tid] = na;
    }
    __syncthreads();
  }
}

// ---------------- host launcher ----------------
extern "C" void kernel_launch(void* const* d_in, const int* in_sizes, int n_in,
                              void* d_out, int out_size, void* d_ws, size_t ws_size,
                              hipStream_t stream)
{
  const int*   recipe = (const int*)d_in[0];
  const int*   g      = (const int*)d_in[1];
  const int*   ingr   = (const int*)d_in[2];
  const float* wv     = (const float*)d_in[3];
  const float* w_ih   = (const float*)d_in[4];
  const float* w_hh   = (const float*)d_in[5];
  const float* b_ih   = (const float*)d_in[6];
  const float* b_hh   = (const float*)d_in[7];
  const float* Z      = (const float*)d_in[8];
  const float* Y      = (const float*)d_in[9];
  const float* Ug     = (const float*)d_in[10];
  const float* z_bias = (const float*)d_in[11];
  const float* y_bias = (const float*)d_in[12];
  const float* S      = (const float*)d_in[13];
  const float* P      = (const float*)d_in[14];
  const float* fcW    = (const float*)d_in[15];
  const float* fcb    = (const float*)d_in[16];
  float* out = (float*)d_out;
  char* ws = (char*)d_ws;

  size_t off = 0;
  unsigned short* wv_b     = (unsigned short*)(ws + off);  off += 16384000;
  unsigned short* wih_b    = (unsigned short*)(ws + off);  off += 655360;
  unsigned short* fcw_b    = (unsigned short*)(ws + off);  off += 16384000;
  unsigned short* whh_f    = (unsigned short*)(ws + off);  off += 655360;
  unsigned short* z_f      = (unsigned short*)(ws + off);  off += 131072;
  unsigned short* p_f      = (unsigned short*)(ws + off);  off += 131072;
  float* gi_ws             = (float*)(ws + off);           off += 10485760;
  float* E_ws              = (float*)(ws + off);           off += 819200;
  float* sumE              = (float*)(ws + off);           off += 16384;
  float* goal_ws           = (float*)(ws + off);           off += 16384;
  float* HT0               = (float*)(ws + off);           off += 16384;
  unsigned short* out_all  = (unsigned short*)(ws + off);  off += 1048576;

  conv_kernel<<<4096, 256, 0, stream>>>(wv, w_ih, fcW, w_hh, Z, P,
                                        wv_b, wih_b, fcw_b, whh_f, z_f, p_f);
  prep_kernel<<<16, 256, 0, stream>>>(g, ingr, wv, Ug, Y, y_bias,
                                      E_ws, sumE, goal_ws, HT0);
  gemm_bf16<0><<<dim3(16, 10), 256, 0, stream>>>(wv_b, wih_b, recipe, b_ih, gi_ws);
  rnn_kernel<<<16, 768, 0, stream>>>(whh_f, z_f, p_f, b_hh, S, z_bias,
                                     gi_ws, goal_ws, E_ws, sumE, HT0,
                                     out_all, out);
  gemm_bf16<1><<<dim3(16, 250), 256, 0, stream>>>(out_all, fcw_b, nullptr, fcb, out);
}